// Round 10
// baseline (182.961 us; speedup 1.0000x reference)
//
#include <hip/hip_runtime.h>
#include <hip/hip_bf16.h>
#include <cstdint>

typedef __bf16 bf16x8 __attribute__((ext_vector_type(8)));
typedef float f32x4 __attribute__((ext_vector_type(4)));

#define MFMA16(a, b, c) __builtin_amdgcn_mfma_f32_16x16x32_bf16((a), (b), (c), 0, 0, 0)

// ---------- helpers ----------
__device__ __forceinline__ unsigned short f2bf(float f) {
  union { float f; unsigned u; } v; v.f = f;
  unsigned u = v.u;
  u += 0x7fffu + ((u >> 16) & 1u);   // RNE (finite data only)
  return (unsigned short)(u >> 16);
}
__device__ __forceinline__ unsigned pk2(float a, float b) {
  __hip_bfloat162 h = __float22bfloat162_rn(make_float2(a, b));  // v_cvt_pk_bf16_f32
  union { __hip_bfloat162 h; unsigned u; } v; v.h = h; return v.u;
}

// ---------- kernel 1: W [1024][128] f32 -> Wt bf16 [3][128][1024] (n-major) ----------
__global__ __launch_bounds__(256) void convert_w(
    const float* __restrict__ Wq, const float* __restrict__ Wk,
    const float* __restrict__ Wv, unsigned short* __restrict__ wt) {
  int idx = blockIdx.x * 256 + threadIdx.x;     // 0 .. 393215
  int m = idx >> 17;
  int rem = idx & 131071;
  int k = rem >> 7;
  int n = rem & 127;
  const float* W = (m == 0) ? Wq : (m == 1) ? Wk : Wv;
  wt[(size_t)m * 131072 + (size_t)n * 1024 + k] = f2bf(W[(size_t)k * 128 + n]);
}

// ---------- kernel 2: QKV projection GEMM ----------
__global__ __launch_bounds__(256) void qkv_gemm(
    const float* __restrict__ x, const unsigned short* __restrict__ wt_all,
    const float* __restrict__ bq, const float* __restrict__ bk,
    const float* __restrict__ bv,
    unsigned short* __restrict__ Qg, unsigned short* __restrict__ Kg,
    unsigned short* __restrict__ Vtg) {
  __shared__ unsigned short x_lds[128][40];   // +8 pad
  __shared__ unsigned short w_lds[128][40];
  const int tid = threadIdx.x;
  const int lane = tid & 63;
  const int w = tid >> 6;
  const int mode = blockIdx.y;
  const int m0 = blockIdx.x * 128;
  const unsigned short* wt = wt_all + (size_t)mode * 131072;
  const float* bias = (mode == 0) ? bq : (mode == 1) ? bk : bv;

  const int wr = (w >> 1) * 64;
  const int wc = (w & 1) * 64;
  const int lr = lane & 15;
  const int lk = (lane >> 4) * 8;

  f32x4 acc[4][4];
#pragma unroll
  for (int m = 0; m < 4; ++m)
#pragma unroll
    for (int n = 0; n < 4; ++n) acc[m][n] = (f32x4){0.f, 0.f, 0.f, 0.f};

  const int srow = tid >> 1;
  const int shalf = (tid & 1) * 16;
  const float* xrow = x + (size_t)(m0 + srow) * 1024 + shalf;
  const unsigned short* wrow = wt + (size_t)srow * 1024 + shalf;

  float4 xa, xb, xc, xd; uint4 wv0, wv1;
  {
    const float4* s4 = (const float4*)xrow;
    xa = s4[0]; xb = s4[1]; xc = s4[2]; xd = s4[3];
    const uint4* ws4 = (const uint4*)wrow;
    wv0 = ws4[0]; wv1 = ws4[1];
  }

  for (int k0 = 0; k0 < 1024; k0 += 32) {
    __syncthreads();
    {
      uint4 w0, w1;
      w0.x = pk2(xa.x, xa.y);  w0.y = pk2(xa.z, xa.w);
      w0.z = pk2(xb.x, xb.y);  w0.w = pk2(xb.z, xb.w);
      w1.x = pk2(xc.x, xc.y);  w1.y = pk2(xc.z, xc.w);
      w1.z = pk2(xd.x, xd.y);  w1.w = pk2(xd.z, xd.w);
      *(uint4*)&x_lds[srow][shalf] = w0;
      *(uint4*)&x_lds[srow][shalf + 8] = w1;
      *(uint4*)&w_lds[srow][shalf] = wv0;
      *(uint4*)&w_lds[srow][shalf + 8] = wv1;
    }
    __syncthreads();
    if (k0 + 32 < 1024) {
      const float4* s4 = (const float4*)(xrow + k0 + 32);
      xa = s4[0]; xb = s4[1]; xc = s4[2]; xd = s4[3];
      const uint4* ws4 = (const uint4*)(wrow + k0 + 32);
      wv0 = ws4[0]; wv1 = ws4[1];
    }
    bf16x8 af[4], bfr[4];
#pragma unroll
    for (int m = 0; m < 4; ++m) af[m] = *(const bf16x8*)&x_lds[wr + m * 16 + lr][lk];
#pragma unroll
    for (int n = 0; n < 4; ++n) bfr[n] = *(const bf16x8*)&w_lds[wc + n * 16 + lr][lk];
#pragma unroll
    for (int m = 0; m < 4; ++m)
#pragma unroll
      for (int n = 0; n < 4; ++n) acc[m][n] = MFMA16(af[m], bfr[n], acc[m][n]);
  }

  float bcol[4];
#pragma unroll
  for (int n = 0; n < 4; ++n) bcol[n] = bias[wc + n * 16 + lr];
#pragma unroll
  for (int m = 0; m < 4; ++m)
#pragma unroll
    for (int n = 0; n < 4; ++n)
#pragma unroll
      for (int r = 0; r < 4; ++r) {
        int grow = m0 + wr + m * 16 + (lane >> 4) * 4 + r;
        int col = wc + n * 16 + lr;
        float val = acc[m][n][r] + bcol[n];
        if (mode == 0) {
          val *= 0.08838834764831845f;  // 1/sqrt(128)
          Qg[(size_t)grow * 128 + col] = f2bf(val);
        } else if (mode == 1) {
          Kg[(size_t)grow * 128 + col] = f2bf(val);
        } else {
          int bb = grow >> 12, s = grow & 4095;
          Vtg[((size_t)bb * 128 + col) * 4096 + s] = f2bf(val);
        }
      }
}

// ---------- attention: K staged in LDS; V read direct from global (L2-pinned) ----------
// Each lane owns q-row q0+w*16+(lane&15); st[f][r] = S[k=k0+16f+4*lg+r][q_own].
struct AttnLds {
  unsigned short K_lds[64][136];   // 17.4 KB
  unsigned short P_lds[4][16][68]; // 8.7 KB   -> 26.1 KB total, 5-6 blocks/CU
};

__device__ __forceinline__ void attn_tiles(
    AttnLds& S, const unsigned short* __restrict__ Kb,
    const unsigned short* __restrict__ Vb, const float* __restrict__ pmb,
    int q0, int tstart, int tend,
    const bf16x8 (&qf)[4], float& mrow, float& lsum, f32x4 (&o)[8]) {
  const int tid = threadIdx.x;
  const int lane = tid & 63;
  const int w = tid >> 6;
  const int lr = lane & 15;
  const int lg = lane >> 4;
  const int lk = lg * 8;
  const int q_own = q0 + w * 16 + lr;

  for (int t = tstart; t < tend; ++t) {
    const int k0 = t * 64;
    __syncthreads();
    {
      // K tile 64x128 bf16 = 16 KB: 4 x uint4 per thread
      int kr = tid >> 2, seg = (tid & 3) * 32;
      const uint4* src = (const uint4*)(Kb + (size_t)(k0 + kr) * 128 + seg);
      uint4 v0 = src[0], v1 = src[1], v2 = src[2], v3 = src[3];
      uint4* dst = (uint4*)&S.K_lds[kr][seg];
      dst[0] = v0; dst[1] = v1; dst[2] = v2; dst[3] = v3;
    }
    __syncthreads();

    // S^T: st[f][r] = S[k = k0+16f+4lg+r][q_own]
    f32x4 st[4];
#pragma unroll
    for (int f = 0; f < 4; ++f) {
      st[f] = (f32x4){0.f, 0.f, 0.f, 0.f};
#pragma unroll
      for (int dc = 0; dc < 4; ++dc) {
        bf16x8 kf = *(const bf16x8*)&S.K_lds[f * 16 + lr][dc * 32 + lk];
        st[f] = MFMA16(kf, qf[dc], st[f]);   // swapped: K as A, Q as B
      }
    }

    // padding mask via ballot (one coalesced load per wave)
    const unsigned long long mb = __ballot(pmb[k0 + lane] > 0.f);
    unsigned nib[4];
#pragma unroll
    for (int f = 0; f < 4; ++f) nib[f] = (unsigned)(mb >> (16 * f + 4 * lg)) & 0xFu;

    float mx = -1e30f;
    if (k0 + 63 > q0 + (w << 4)) {           // diagonal tile: causal + pad
#pragma unroll
      for (int f = 0; f < 4; ++f)
#pragma unroll
        for (int r = 0; r < 4; ++r) {
          const bool ok = (((nib[f] >> r) & 1u) != 0u) &&
                          (k0 + 16 * f + 4 * lg + r <= q_own);
          const float s = ok ? st[f][r] : -1e30f;
          st[f][r] = s;
          mx = fmaxf(mx, s);
        }
    } else {                                  // interior tile: pad mask only
#pragma unroll
      for (int f = 0; f < 4; ++f)
#pragma unroll
        for (int r = 0; r < 4; ++r) {
          const bool ok = ((nib[f] >> r) & 1u) != 0u;
          const float s = ok ? st[f][r] : -1e30f;
          st[f][r] = s;
          mx = fmaxf(mx, s);
        }
    }
    mx = fmaxf(mx, __shfl_xor(mx, 16));
    mx = fmaxf(mx, __shfl_xor(mx, 32));
    const float mnew = fmaxf(mrow, mx);
    const float alpha = __expf(mrow - mnew);
    mrow = mnew;

    float sum = 0.f;
#pragma unroll
    for (int f = 0; f < 4; ++f) {
      const float p0 = (st[f][0] < -1e29f) ? 0.f : __expf(st[f][0] - mnew);
      const float p1 = (st[f][1] < -1e29f) ? 0.f : __expf(st[f][1] - mnew);
      const float p2 = (st[f][2] < -1e29f) ? 0.f : __expf(st[f][2] - mnew);
      const float p3 = (st[f][3] < -1e29f) ? 0.f : __expf(st[f][3] - mnew);
      sum += (p0 + p1) + (p2 + p3);
      uint2 u; u.x = pk2(p0, p1); u.y = pk2(p2, p3);
      *(uint2*)&S.P_lds[w][lr][16 * f + 4 * lg] = u;   // P[q_own][k-chunk]
    }
    sum += __shfl_xor(sum, 16);
    sum += __shfl_xor(sum, 32);
    lsum = lsum * alpha + sum;
#pragma unroll
    for (int n = 0; n < 8; ++n) o[n] *= alpha;

    __asm__ volatile("s_waitcnt lgkmcnt(0)" ::: "memory");
    // O^T: o[n][r] = O[q_own][d = n*16+4lg+r]; V fragments direct from global (L2)
#pragma unroll
    for (int kc = 0; kc < 2; ++kc) {
      bf16x8 pa = *(const bf16x8*)&S.P_lds[w][lr][kc * 32 + lk];
#pragma unroll
      for (int n = 0; n < 8; ++n) {
        bf16x8 vf = *(const bf16x8*)(Vb + (size_t)(n * 16 + lr) * 4096 + k0 + kc * 32 + lk);
        o[n] = MFMA16(vf, pa, o[n]);         // swapped: V as A, P as B
      }
    }
  }
}

// ---------- kernel 3a: fallback monolithic flash attention ----------
__global__ __launch_bounds__(256, 5) void attn_fwd(
    const unsigned short* __restrict__ Qg, const unsigned short* __restrict__ Kg,
    const unsigned short* __restrict__ Vtg, const float* __restrict__ pmask,
    float* __restrict__ out) {
  __shared__ AttnLds S;
  const int tid = threadIdx.x;
  const int lane = tid & 63;
  const int w = tid >> 6;
  const int b = blockIdx.y;
  const int q0 = blockIdx.x * 64;
  const int lr = lane & 15;
  const int lg = lane >> 4;
  const int lk = lg * 8;

  bf16x8 qf[4];
  {
    const unsigned short* qp = Qg + ((size_t)b * 4096 + q0 + w * 16 + lr) * 128;
#pragma unroll
    for (int dc = 0; dc < 4; ++dc) qf[dc] = *(const bf16x8*)(qp + dc * 32 + lk);
  }
  float mrow = -1e30f, lsum = 0.f;
  f32x4 o[8];
#pragma unroll
  for (int n = 0; n < 8; ++n) o[n] = (f32x4){0.f, 0.f, 0.f, 0.f};

  attn_tiles(S, Kg + (size_t)b * 4096 * 128, Vtg + (size_t)b * 128 * 4096,
             pmask + (size_t)b * 4096, q0, 0, (q0 >> 6) + 1, qf, mrow, lsum, o);

  const int qrow = q0 + w * 16 + lr;
  const bool alive = pmask[(size_t)b * 4096 + qrow] > 0.f;
  const float inv = (alive && lsum > 0.f) ? 1.f / lsum : 0.f;
  float* op = out + ((size_t)b * 4096 + qrow) * 128 + 4 * lg;
#pragma unroll
  for (int n = 0; n < 8; ++n) {
    f32x4 v = o[n] * inv;
    *(f32x4*)(op + n * 16) = v;
  }
}

// ---------- kernel 3b: split-KV, XCD-pinned, chunk=8, bf16 partials ----------
// 1152 blocks (<=1280 co-resident at 5/CU). xcd = L&7; batch = xcd>>1;
// s = 0..287 within batch. group g=qb>>3 has 8*(g+1) items starting at 4g(g+1).
__global__ __launch_bounds__(256, 5) void attn_split(
    const unsigned short* __restrict__ Qg, const unsigned short* __restrict__ Kg,
    const unsigned short* __restrict__ Vtg, const float* __restrict__ pmask,
    float* __restrict__ out, unsigned short* __restrict__ o_part,
    float* __restrict__ ml_part) {
  __shared__ AttnLds S;
  const int tid = threadIdx.x;
  const int lane = tid & 63;
  const int w = tid >> 6;
  const int L = blockIdx.x;
  const int xcd = L & 7;
  const int b = xcd >> 1;
  const int s = ((L >> 3) << 1) | (xcd & 1);   // 0..287 within batch
  int qb, c, nch;
  if (s < 8) {
    qb = s; c = 0; nch = 1;
  } else {
    int g = 1;
#pragma unroll
    for (int gg = 2; gg <= 7; ++gg)
      if (s >= 4 * gg * (gg + 1)) g = gg;
    const int rel = s - 4 * g * (g + 1);
    const int qq = rel / (g + 1);
    qb = 8 * g + qq;
    c = rel - qq * (g + 1);
    nch = g + 1;
  }
  const int q0 = qb * 64;
  const int tstart = c * 8;
  const int tend = min(c * 8 + 8, qb + 1);
  const int lr = lane & 15;
  const int lg = lane >> 4;
  const int lk = lg * 8;

  bf16x8 qf[4];
  {
    const unsigned short* qp = Qg + ((size_t)b * 4096 + q0 + w * 16 + lr) * 128;
#pragma unroll
    for (int dc = 0; dc < 4; ++dc) qf[dc] = *(const bf16x8*)(qp + dc * 32 + lk);
  }
  float mrow = -1e30f, lsum = 0.f;
  f32x4 o[8];
#pragma unroll
  for (int n = 0; n < 8; ++n) o[n] = (f32x4){0.f, 0.f, 0.f, 0.f};

  attn_tiles(S, Kg + (size_t)b * 4096 * 128, Vtg + (size_t)b * 128 * 4096,
             pmask + (size_t)b * 4096, q0, tstart, tend, qf, mrow, lsum, o);

  if (nch == 1) {
    const int qrow = q0 + w * 16 + lr;
    const bool alive = pmask[(size_t)b * 4096 + qrow] > 0.f;
    const float inv = (alive && lsum > 0.f) ? 1.f / lsum : 0.f;
    float* op = out + ((size_t)b * 4096 + qrow) * 128 + 4 * lg;
#pragma unroll
    for (int n = 0; n < 8; ++n) {
      f32x4 v = o[n] * inv;
      *(f32x4*)(op + n * 16) = v;
    }
  } else {
    const int slot = b * 280 + (s - 8);
    unsigned short* op = o_part + ((size_t)slot * 64 + w * 16 + lr) * 128 + 4 * lg;
#pragma unroll
    for (int n = 0; n < 8; ++n) {
      uint2 u; u.x = pk2(o[n][0], o[n][1]); u.y = pk2(o[n][2], o[n][3]);
      *(uint2*)(op + n * 16) = u;
    }
    if (lane < 16) {
      float* mp = ml_part + ((size_t)slot * 64 + w * 16 + lane) * 2;
      mp[0] = mrow;
      mp[1] = lsum;
    }
  }
}

// ---------- kernel 3c: combine partials (qb >= 8), one wave per output row ----------
__global__ __launch_bounds__(256) void attn_combine(
    const unsigned short* __restrict__ o_part, const float* __restrict__ ml_part,
    const float* __restrict__ pmask, float* __restrict__ out) {
  const int tid = threadIdx.x;
  const int lane = tid & 63;
  const int w = tid >> 6;
  const int g = blockIdx.x * 4 + w;      // 0 .. 14335
  const int b = g / 3584;
  const int rem = g % 3584;
  const int qb = 8 + (rem >> 6);
  const int row = rem & 63;
  const int qrow = qb * 64 + row;
  const int grp = qb >> 3;               // 1..7
  const int nch = grp + 1;               // 2..8
  const int pbase = b * 280 + 4 * grp * (grp + 1) - 8 + (qb - 8 * grp) * nch;

  float m[8], l[8];
  float M = -1e30f;
#pragma unroll
  for (int c = 0; c < 8; ++c)
    if (c < nch) {
      const float* mp = ml_part + ((size_t)(pbase + c) * 64 + row) * 2;
      m[c] = mp[0];
      l[c] = mp[1];
      M = fmaxf(M, m[c]);
    }
  float L = 0.f, wgt[8];
#pragma unroll
  for (int c = 0; c < 8; ++c)
    if (c < nch) {
      wgt[c] = __expf(m[c] - M);
      L += wgt[c] * l[c];
    }
  float2 acc = {0.f, 0.f};
#pragma unroll
  for (int c = 0; c < 8; ++c)
    if (c < nch) {
      const unsigned u = *(const unsigned*)(o_part + ((size_t)(pbase + c) * 64 + row) * 128 + lane * 2);
      acc.x += wgt[c] * __uint_as_float(u << 16);
      acc.y += wgt[c] * __uint_as_float(u & 0xffff0000u);
    }
  const bool alive = pmask[(size_t)b * 4096 + qrow] > 0.f;
  const float inv = (alive && L > 0.f) ? 1.f / L : 0.f;
  float2* op = (float2*)(out + ((size_t)b * 4096 + qrow) * 128);
  op[lane] = make_float2(acc.x * inv, acc.y * inv);
}

extern "C" void kernel_launch(void* const* d_in, const int* in_sizes, int n_in,
                              void* d_out, int out_size, void* d_ws, size_t ws_size,
                              hipStream_t stream) {
  (void)in_sizes; (void)n_in; (void)out_size;
  const float* x  = (const float*)d_in[0];
  const float* pm = (const float*)d_in[1];
  const float* Wq = (const float*)d_in[2];
  const float* bq = (const float*)d_in[3];
  const float* Wk = (const float*)d_in[4];
  const float* bk = (const float*)d_in[5];
  const float* Wv = (const float*)d_in[6];
  const float* bv = (const float*)d_in[7];
  float* out = (float*)d_out;

  unsigned short* ws  = (unsigned short*)d_ws;
  unsigned short* wt  = ws;                    // 3*128*1024   = 393216 shorts
  unsigned short* Qg  = ws + 393216;           // 16384*128    = 2097152
  unsigned short* Kg  = Qg + 2097152;
  unsigned short* Vtg = Kg + 2097152;          // QKV+wt = 13.37 MB
  unsigned short* o_part = ws + 6684672;       // 1120 slots * 64 * 128 bf16 = 18.35 MB
  float* ml_part = (float*)(ws + 15859712);    // 1120*64*2 f32 = 0.57 MB
  const size_t WS_NEED = 15859712u * 2u + 573440u;  // 32.3 MB

  convert_w<<<1536, 256, 0, stream>>>(Wq, Wk, Wv, wt);
  qkv_gemm<<<dim3(128, 3), 256, 0, stream>>>(x, wt, bq, bk, bv, Qg, Kg, Vtg);
  if (ws_size >= WS_NEED) {
    attn_split<<<1152, 256, 0, stream>>>(Qg, Kg, Vtg, pm, out, o_part, ml_part);
    attn_combine<<<3584, 256, 0, stream>>>(o_part, ml_part, pm, out);
  } else {
    attn_fwd<<<dim3(64, 4), 256, 0, stream>>>(Qg, Kg, Vtg, pm, out);
  }
}

// Round 11
// 104.368 us; speedup vs baseline: 1.7530x; 1.7530x over previous
//
#include <hip/hip_runtime.h>
#include <hip/hip_bf16.h>
#include <cstdint>

typedef __bf16 bf16x8 __attribute__((ext_vector_type(8)));
typedef float f32x4 __attribute__((ext_vector_type(4)));

#define MFMA16(a, b, c) __builtin_amdgcn_mfma_f32_16x16x32_bf16((a), (b), (c), 0, 0, 0)

// ---------- helpers ----------
__device__ __forceinline__ unsigned short f2bf(float f) {
  union { float f; unsigned u; } v; v.f = f;
  unsigned u = v.u;
  u += 0x7fffu + ((u >> 16) & 1u);   // RNE (finite data only)
  return (unsigned short)(u >> 16);
}
__device__ __forceinline__ unsigned pk2(float a, float b) {
  __hip_bfloat162 h = __float22bfloat162_rn(make_float2(a, b));  // v_cvt_pk_bf16_f32
  union { __hip_bfloat162 h; unsigned u; } v; v.h = h; return v.u;
}

// ---------- kernel 1: W [1024][128] f32 -> Wt bf16 [3][128][1024] (n-major) ----------
__global__ __launch_bounds__(256) void convert_w(
    const float* __restrict__ Wq, const float* __restrict__ Wk,
    const float* __restrict__ Wv, unsigned short* __restrict__ wt) {
  int idx = blockIdx.x * 256 + threadIdx.x;     // 0 .. 393215
  int m = idx >> 17;
  int rem = idx & 131071;
  int k = rem >> 7;
  int n = rem & 127;
  const float* W = (m == 0) ? Wq : (m == 1) ? Wk : Wv;
  wt[(size_t)m * 131072 + (size_t)n * 1024 + k] = f2bf(W[(size_t)k * 128 + n]);
}

// ---------- kernel 2: QKV projection GEMM, 64-row tiles (768 blocks, 3/CU) ----------
__global__ __launch_bounds__(256) void qkv_gemm(
    const float* __restrict__ x, const unsigned short* __restrict__ wt_all,
    const float* __restrict__ bq, const float* __restrict__ bk,
    const float* __restrict__ bv,
    unsigned short* __restrict__ Qg, unsigned short* __restrict__ Kg,
    unsigned short* __restrict__ Vtg) {
  __shared__ unsigned short x_lds[64][40];    // +8 pad
  __shared__ unsigned short w_lds[128][40];
  const int tid = threadIdx.x;
  const int lane = tid & 63;
  const int w = tid >> 6;
  const int mode = blockIdx.y;
  const int m0 = blockIdx.x * 64;
  const unsigned short* wt = wt_all + (size_t)mode * 131072;
  const float* bias = (mode == 0) ? bq : (mode == 1) ? bk : bv;

  const int wr = (w >> 1) * 32;     // 0 or 32
  const int wc = (w & 1) * 64;      // 0 or 64
  const int lr = lane & 15;
  const int lk = (lane >> 4) * 8;

  f32x4 acc[2][4];
#pragma unroll
  for (int m = 0; m < 2; ++m)
#pragma unroll
    for (int n = 0; n < 4; ++n) acc[m][n] = (f32x4){0.f, 0.f, 0.f, 0.f};

  const int xr = tid >> 2;                 // 0..63
  const int xc = (tid & 3) * 8;            // 0,8,16,24
  const int srow = tid >> 1;               // 0..127
  const int shalf = (tid & 1) * 16;
  const float* xrow = x + (size_t)(m0 + xr) * 1024 + xc;
  const unsigned short* wrow = wt + (size_t)srow * 1024 + shalf;

  float4 xa, xb; uint4 wv0, wv1;
  {
    const float4* s4 = (const float4*)xrow;
    xa = s4[0]; xb = s4[1];
    const uint4* ws4 = (const uint4*)wrow;
    wv0 = ws4[0]; wv1 = ws4[1];
  }

  for (int k0 = 0; k0 < 1024; k0 += 32) {
    __syncthreads();
    {
      uint4 xw;
      xw.x = pk2(xa.x, xa.y);  xw.y = pk2(xa.z, xa.w);
      xw.z = pk2(xb.x, xb.y);  xw.w = pk2(xb.z, xb.w);
      *(uint4*)&x_lds[xr][xc] = xw;
      *(uint4*)&w_lds[srow][shalf] = wv0;
      *(uint4*)&w_lds[srow][shalf + 8] = wv1;
    }
    __syncthreads();
    if (k0 + 32 < 1024) {
      const float4* s4 = (const float4*)(xrow + k0 + 32);
      xa = s4[0]; xb = s4[1];
      const uint4* ws4 = (const uint4*)(wrow + k0 + 32);
      wv0 = ws4[0]; wv1 = ws4[1];
    }
    bf16x8 af[2], bfr[4];
#pragma unroll
    for (int m = 0; m < 2; ++m) af[m] = *(const bf16x8*)&x_lds[wr + m * 16 + lr][lk];
#pragma unroll
    for (int n = 0; n < 4; ++n) bfr[n] = *(const bf16x8*)&w_lds[wc + n * 16 + lr][lk];
#pragma unroll
    for (int m = 0; m < 2; ++m)
#pragma unroll
      for (int n = 0; n < 4; ++n) acc[m][n] = MFMA16(af[m], bfr[n], acc[m][n]);
  }

  float bcol[4];
#pragma unroll
  for (int n = 0; n < 4; ++n) bcol[n] = bias[wc + n * 16 + lr];
#pragma unroll
  for (int m = 0; m < 2; ++m)
#pragma unroll
    for (int n = 0; n < 4; ++n)
#pragma unroll
      for (int r = 0; r < 4; ++r) {
        int grow = m0 + wr + m * 16 + (lane >> 4) * 4 + r;
        int col = wc + n * 16 + lr;
        float val = acc[m][n][r] + bcol[n];
        if (mode == 0) {
          val *= 0.08838834764831845f;  // 1/sqrt(128)
          Qg[(size_t)grow * 128 + col] = f2bf(val);
        } else if (mode == 1) {
          Kg[(size_t)grow * 128 + col] = f2bf(val);
        } else {
          int bb = grow >> 12, s = grow & 4095;
          Vtg[((size_t)bb * 128 + col) * 4096 + s] = f2bf(val);
        }
      }
}

// ---------- attention LDS: P overlays K (K dead after QK^T) -> 35 KB, 4 blocks/CU ----------
struct AttnLds {
  union {
    unsigned short K_lds[64][136];    // 17408 B
    unsigned short P_lds[4][16][68];  //  8704 B (within K region)
  } u;
  unsigned short V_lds[128][72];      // 18432 B
};

__device__ __forceinline__ void attn_tiles(
    AttnLds& S, const unsigned short* __restrict__ Kb,
    const unsigned short* __restrict__ Vb, const float* __restrict__ pmb,
    int q0, int tstart, int tend,
    const bf16x8 (&qf)[4], float& mrow, float& lsum, f32x4 (&o)[8]) {
  const int tid = threadIdx.x;
  const int lane = tid & 63;
  const int w = tid >> 6;
  const int lr = lane & 15;
  const int lg = lane >> 4;
  const int lk = lg * 8;
  const int q_own = q0 + w * 16 + lr;

  for (int t = tstart; t < tend; ++t) {
    const int k0 = t * 64;
    __syncthreads();            // (A) prev tile's PV reads done
    {
      int kr = tid >> 2, seg = (tid & 3) * 32;
      const uint4* src = (const uint4*)(Kb + (size_t)(k0 + kr) * 128 + seg);
      uint4 v0 = src[0], v1 = src[1], v2 = src[2], v3 = src[3];
      uint4* dst = (uint4*)&S.u.K_lds[kr][seg];
      dst[0] = v0; dst[1] = v1; dst[2] = v2; dst[3] = v3;
      int d = tid >> 1, half = (tid & 1) * 32;
      const uint4* vs = (const uint4*)(Vb + (size_t)d * 4096 + k0 + half);
      uint4 u0 = vs[0], u1 = vs[1], u2 = vs[2], u3 = vs[3];
      uint4* vdst = (uint4*)&S.V_lds[d][half];
      vdst[0] = u0; vdst[1] = u1; vdst[2] = u2; vdst[3] = u3;
    }
    __syncthreads();            // (B) staging visible

    // S^T: st[f][r] = S[k = k0+16f+4lg+r][q_own]
    f32x4 st[4];
#pragma unroll
    for (int f = 0; f < 4; ++f) {
      st[f] = (f32x4){0.f, 0.f, 0.f, 0.f};
#pragma unroll
      for (int dc = 0; dc < 4; ++dc) {
        bf16x8 kf = *(const bf16x8*)&S.u.K_lds[f * 16 + lr][dc * 32 + lk];
        st[f] = MFMA16(kf, qf[dc], st[f]);   // swapped: K as A, Q as B
      }
    }

    // padding mask via ballot (one coalesced load per wave)
    const unsigned long long mb = __ballot(pmb[k0 + lane] > 0.f);
    unsigned nib[4];
#pragma unroll
    for (int f = 0; f < 4; ++f) nib[f] = (unsigned)(mb >> (16 * f + 4 * lg)) & 0xFu;

    __syncthreads();            // (C) all K reads done -> P may overwrite K region

    float mx = -1e30f;
    if (k0 + 63 > q0 + (w << 4)) {           // diagonal tile: causal + pad
#pragma unroll
      for (int f = 0; f < 4; ++f)
#pragma unroll
        for (int r = 0; r < 4; ++r) {
          const bool ok = (((nib[f] >> r) & 1u) != 0u) &&
                          (k0 + 16 * f + 4 * lg + r <= q_own);
          const float s = ok ? st[f][r] : -1e30f;
          st[f][r] = s;
          mx = fmaxf(mx, s);
        }
    } else {                                  // interior tile: pad mask only
#pragma unroll
      for (int f = 0; f < 4; ++f)
#pragma unroll
        for (int r = 0; r < 4; ++r) {
          const bool ok = ((nib[f] >> r) & 1u) != 0u;
          const float s = ok ? st[f][r] : -1e30f;
          st[f][r] = s;
          mx = fmaxf(mx, s);
        }
    }
    mx = fmaxf(mx, __shfl_xor(mx, 16));
    mx = fmaxf(mx, __shfl_xor(mx, 32));
    const float mnew = fmaxf(mrow, mx);
    const float alpha = __expf(mrow - mnew);
    mrow = mnew;

    float sum = 0.f;
#pragma unroll
    for (int f = 0; f < 4; ++f) {
      const float p0 = (st[f][0] < -1e29f) ? 0.f : __expf(st[f][0] - mnew);
      const float p1 = (st[f][1] < -1e29f) ? 0.f : __expf(st[f][1] - mnew);
      const float p2 = (st[f][2] < -1e29f) ? 0.f : __expf(st[f][2] - mnew);
      const float p3 = (st[f][3] < -1e29f) ? 0.f : __expf(st[f][3] - mnew);
      sum += (p0 + p1) + (p2 + p3);
      uint2 u; u.x = pk2(p0, p1); u.y = pk2(p2, p3);
      *(uint2*)&S.u.P_lds[w][lr][16 * f + 4 * lg] = u;   // P[q_own][k-chunk]
    }
    sum += __shfl_xor(sum, 16);
    sum += __shfl_xor(sum, 32);
    lsum = lsum * alpha + sum;
#pragma unroll
    for (int n = 0; n < 8; ++n) o[n] *= alpha;

    __asm__ volatile("s_waitcnt lgkmcnt(0)" ::: "memory");
    // O^T: o[n][r] = O[q_own][d = n*16+4lg+r]
#pragma unroll
    for (int kc = 0; kc < 2; ++kc) {
      bf16x8 pa = *(const bf16x8*)&S.u.P_lds[w][lr][kc * 32 + lk];
#pragma unroll
      for (int n = 0; n < 8; ++n) {
        bf16x8 vf = *(const bf16x8*)&S.V_lds[n * 16 + lr][kc * 32 + lk];
        o[n] = MFMA16(vf, pa, o[n]);         // swapped: V as A, P as B
      }
    }
  }
}

// ---------- kernel 3a: fallback monolithic flash attention ----------
__global__ __launch_bounds__(256, 4) void attn_fwd(
    const unsigned short* __restrict__ Qg, const unsigned short* __restrict__ Kg,
    const unsigned short* __restrict__ Vtg, const float* __restrict__ pmask,
    float* __restrict__ out) {
  __shared__ AttnLds S;
  const int tid = threadIdx.x;
  const int lane = tid & 63;
  const int w = tid >> 6;
  const int b = blockIdx.y;
  const int q0 = blockIdx.x * 64;
  const int lr = lane & 15;
  const int lg = lane >> 4;
  const int lk = lg * 8;

  bf16x8 qf[4];
  {
    const unsigned short* qp = Qg + ((size_t)b * 4096 + q0 + w * 16 + lr) * 128;
#pragma unroll
    for (int dc = 0; dc < 4; ++dc) qf[dc] = *(const bf16x8*)(qp + dc * 32 + lk);
  }
  float mrow = -1e30f, lsum = 0.f;
  f32x4 o[8];
#pragma unroll
  for (int n = 0; n < 8; ++n) o[n] = (f32x4){0.f, 0.f, 0.f, 0.f};

  attn_tiles(S, Kg + (size_t)b * 4096 * 128, Vtg + (size_t)b * 128 * 4096,
             pmask + (size_t)b * 4096, q0, 0, (q0 >> 6) + 1, qf, mrow, lsum, o);

  const int qrow = q0 + w * 16 + lr;
  const bool alive = pmask[(size_t)b * 4096 + qrow] > 0.f;
  const float inv = (alive && lsum > 0.f) ? 1.f / lsum : 0.f;
  float* op = out + ((size_t)b * 4096 + qrow) * 128 + 4 * lg;
#pragma unroll
  for (int n = 0; n < 8; ++n) {
    f32x4 v = o[n] * inv;
    *(f32x4*)(op + n * 16) = v;
  }
}

// ---------- kernel 3b: split-KV, XCD-pinned, chunk=8, bf16 partials ----------
// 1152 blocks. xcd = L&7; batch = xcd>>1; s = 0..287 within batch.
// group g=qb>>3 has 8*(g+1) items starting at 4g(g+1).
__global__ __launch_bounds__(256, 4) void attn_split(
    const unsigned short* __restrict__ Qg, const unsigned short* __restrict__ Kg,
    const unsigned short* __restrict__ Vtg, const float* __restrict__ pmask,
    float* __restrict__ out, unsigned short* __restrict__ o_part,
    float* __restrict__ ml_part) {
  __shared__ AttnLds S;
  const int tid = threadIdx.x;
  const int lane = tid & 63;
  const int w = tid >> 6;
  const int L = blockIdx.x;
  const int xcd = L & 7;
  const int b = xcd >> 1;
  const int s = ((L >> 3) << 1) | (xcd & 1);   // 0..287 within batch
  int qb, c, nch;
  if (s < 8) {
    qb = s; c = 0; nch = 1;
  } else {
    int g = 1;
#pragma unroll
    for (int gg = 2; gg <= 7; ++gg)
      if (s >= 4 * gg * (gg + 1)) g = gg;
    const int rel = s - 4 * g * (g + 1);
    const int qq = rel / (g + 1);
    qb = 8 * g + qq;
    c = rel - qq * (g + 1);
    nch = g + 1;
  }
  const int q0 = qb * 64;
  const int tstart = c * 8;
  const int tend = min(c * 8 + 8, qb + 1);
  const int lr = lane & 15;
  const int lg = lane >> 4;
  const int lk = lg * 8;

  bf16x8 qf[4];
  {
    const unsigned short* qp = Qg + ((size_t)b * 4096 + q0 + w * 16 + lr) * 128;
#pragma unroll
    for (int dc = 0; dc < 4; ++dc) qf[dc] = *(const bf16x8*)(qp + dc * 32 + lk);
  }
  float mrow = -1e30f, lsum = 0.f;
  f32x4 o[8];
#pragma unroll
  for (int n = 0; n < 8; ++n) o[n] = (f32x4){0.f, 0.f, 0.f, 0.f};

  attn_tiles(S, Kg + (size_t)b * 4096 * 128, Vtg + (size_t)b * 128 * 4096,
             pmask + (size_t)b * 4096, q0, tstart, tend, qf, mrow, lsum, o);

  if (nch == 1) {
    const int qrow = q0 + w * 16 + lr;
    const bool alive = pmask[(size_t)b * 4096 + qrow] > 0.f;
    const float inv = (alive && lsum > 0.f) ? 1.f / lsum : 0.f;
    float* op = out + ((size_t)b * 4096 + qrow) * 128 + 4 * lg;
#pragma unroll
    for (int n = 0; n < 8; ++n) {
      f32x4 v = o[n] * inv;
      *(f32x4*)(op + n * 16) = v;
    }
  } else {
    const int slot = b * 280 + (s - 8);
    unsigned short* op = o_part + ((size_t)slot * 64 + w * 16 + lr) * 128 + 4 * lg;
#pragma unroll
    for (int n = 0; n < 8; ++n) {
      uint2 u; u.x = pk2(o[n][0], o[n][1]); u.y = pk2(o[n][2], o[n][3]);
      *(uint2*)(op + n * 16) = u;
    }
    if (lane < 16) {
      float* mp = ml_part + ((size_t)slot * 64 + w * 16 + lane) * 2;
      mp[0] = mrow;
      mp[1] = lsum;
    }
  }
}

// ---------- kernel 3c: combine partials (qb >= 8), one wave per output row ----------
__global__ __launch_bounds__(256) void attn_combine(
    const unsigned short* __restrict__ o_part, const float* __restrict__ ml_part,
    const float* __restrict__ pmask, float* __restrict__ out) {
  const int tid = threadIdx.x;
  const int lane = tid & 63;
  const int w = tid >> 6;
  const int g = blockIdx.x * 4 + w;      // 0 .. 14335
  const int b = g / 3584;
  const int rem = g % 3584;
  const int qb = 8 + (rem >> 6);
  const int row = rem & 63;
  const int qrow = qb * 64 + row;
  const int grp = qb >> 3;               // 1..7
  const int nch = grp + 1;               // 2..8
  const int pbase = b * 280 + 4 * grp * (grp + 1) - 8 + (qb - 8 * grp) * nch;

  float m[8], l[8];
  float M = -1e30f;
#pragma unroll
  for (int c = 0; c < 8; ++c)
    if (c < nch) {
      const float* mp = ml_part + ((size_t)(pbase + c) * 64 + row) * 2;
      m[c] = mp[0];
      l[c] = mp[1];
      M = fmaxf(M, m[c]);
    }
  float L = 0.f, wgt[8];
#pragma unroll
  for (int c = 0; c < 8; ++c)
    if (c < nch) {
      wgt[c] = __expf(m[c] - M);
      L += wgt[c] * l[c];
    }
  float2 acc = {0.f, 0.f};
#pragma unroll
  for (int c = 0; c < 8; ++c)
    if (c < nch) {
      const unsigned u = *(const unsigned*)(o_part + ((size_t)(pbase + c) * 64 + row) * 128 + lane * 2);
      acc.x += wgt[c] * __uint_as_float(u << 16);
      acc.y += wgt[c] * __uint_as_float(u & 0xffff0000u);
    }
  const bool alive = pmask[(size_t)b * 4096 + qrow] > 0.f;
  const float inv = (alive && L > 0.f) ? 1.f / L : 0.f;
  float2* op = (float2*)(out + ((size_t)b * 4096 + qrow) * 128);
  op[lane] = make_float2(acc.x * inv, acc.y * inv);
}

extern "C" void kernel_launch(void* const* d_in, const int* in_sizes, int n_in,
                              void* d_out, int out_size, void* d_ws, size_t ws_size,
                              hipStream_t stream) {
  (void)in_sizes; (void)n_in; (void)out_size;
  const float* x  = (const float*)d_in[0];
  const float* pm = (const float*)d_in[1];
  const float* Wq = (const float*)d_in[2];
  const float* bq = (const float*)d_in[3];
  const float* Wk = (const float*)d_in[4];
  const float* bk = (const float*)d_in[5];
  const float* Wv = (const float*)d_in[6];
  const float* bv = (const float*)d_in[7];
  float* out = (float*)d_out;

  unsigned short* ws  = (unsigned short*)d_ws;
  unsigned short* wt  = ws;                    // 3*128*1024   = 393216 shorts
  unsigned short* Qg  = ws + 393216;           // 16384*128    = 2097152
  unsigned short* Kg  = Qg + 2097152;
  unsigned short* Vtg = Kg + 2097152;          // QKV+wt = 13.37 MB
  unsigned short* o_part = ws + 6684672;       // 1120 slots * 64 * 128 bf16 = 18.35 MB
  float* ml_part = (float*)(ws + 15859712);    // 1120*64*2 f32 = 0.57 MB
  const size_t WS_NEED = 15859712u * 2u + 573440u;  // 32.3 MB

  convert_w<<<1536, 256, 0, stream>>>(Wq, Wk, Wv, wt);
  qkv_gemm<<<dim3(256, 3), 256, 0, stream>>>(x, wt, bq, bk, bv, Qg, Kg, Vtg);
  if (ws_size >= WS_NEED) {
    attn_split<<<1152, 256, 0, stream>>>(Qg, Kg, Vtg, pm, out, o_part, ml_part);
    attn_combine<<<3584, 256, 0, stream>>>(o_part, ml_part, pm, out);
  } else {
    attn_fwd<<<dim3(64, 4), 256, 0, stream>>>(Qg, Kg, Vtg, pm, out);
  }
}